// Round 8
// baseline (98.207 us; speedup 1.0000x reference)
//
#include <hip/hip_runtime.h>
#include <stdint.h>

#pragma clang fp contract(off)

#define NA 10
#define LL 4096
#define NB 4
#define NSEL (LL * NA)        // 40960 proposals per image
#define PRE2 2048             // NMS candidate window (prefix-stable: 300 kept << 2048)
#define POST_NMS 300
#define CAND 4096             // candidate buffer (12-bit threshold overshoot bound)
#define NHB12 4096            // 12-bit-prefix histogram buckets
#define TWORDS 33792          // col-major mask words per image: 64 * sum_{w=0..31}(w+1)

__constant__ float c_WS[NA] = {16.f, 32.f, 40.f, 48.f, 64.f, 72.f, 80.f, 96.f, 112.f, 128.f};

// async global->LDS DMA: per-lane 16B from g (per-lane addr), lands at uniform dst + lane*16
__device__ inline void gload_lds16(const void* g, void* l) {
    __builtin_amdgcn_global_load_lds(
        (const __attribute__((address_space(1))) unsigned*)g,
        (__attribute__((address_space(3))) unsigned*)l, 16, 0, 0);
}

// ---------------- Kernel 1: decode (1 anchor-row per block) + 12-bit partial hist ----------------
// Wide decode (40 blocks, one per (image,anchor): c_WS[a] scalar, coalesced row reads);
// each block stores a 4096-bucket (key>>20) partial hist to its OWN slot (plain stores:
// no memset node, no global atomics). 12-bit threshold = survivor SUPERSET of top-2048;
// k_rank reconstructs the exact order, so output is bit-identical.
__global__ __launch_bounds__(1024) void k_prep(const float* __restrict__ scores,
                                               const float* __restrict__ deltas,
                                               unsigned long long* __restrict__ packed,
                                               float2* __restrict__ prop,
                                               unsigned* __restrict__ hpart) {
    __shared__ unsigned shist[NHB12];    // 16 KB
    const int tid = threadIdx.x;
    const int a = blockIdx.x;            // anchor = row
    const int b = blockIdx.y;

    #pragma unroll
    for (int i = 0; i < 4; ++i) shist[i * 1024 + tid] = 0;
    __syncthreads();

    const float4 s4  = ((const float4*)scores)[((b * 20 + 10 + a) << 10) + tid];
    const float4 d04 = ((const float4*)deltas)[((b * 20 + 2 * a) << 10) + tid];
    const float4 d14 = ((const float4*)deltas)[((b * 20 + 2 * a + 1) << 10) + tid];
    const float w = c_WS[a];
    const int l0 = tid << 2;             // l = 4*tid + k
    const int r = (a << 12) + l0;

    unsigned key[4];
    float x1v[4], x2v[4];
    #pragma unroll
    for (int k = 0; k < 4; ++k) {
        const float d0 = (k == 0) ? d04.x : (k == 1) ? d04.y : (k == 2) ? d04.z : d04.w;
        const float d1 = (k == 0) ? d14.x : (k == 1) ? d14.y : (k == 2) ? d14.z : d14.w;
        float sv      = (k == 0) ? s4.x  : (k == 1) ? s4.y  : (k == 2) ? s4.z  : s4.w;
        const float ctr = (float)(8 * (l0 + k) + 4);
        const float pc = d0 * w + ctr;   // contract(off): mul then add, matches numpy
        const float pl = expf(d1) * w;
        const float x1 = fminf(fmaxf(pc - 0.5f * pl, 0.0f), 32767.0f);
        const float x2 = fminf(fmaxf(pc + 0.5f * pl, 0.0f), 32767.0f);
        if (x2 - x1 + 1.0f < 8.0f) sv = 0.0f;
        const unsigned u = __float_as_uint(sv);
        key[k] = (u & 0x80000000u) ? ~u : (u | 0x80000000u);   // ascending uint == ascending float
        x1v[k] = x1; x2v[k] = x2;
    }
    // packed: reference flat index i = l*NA + a, inverted for descending tie-break
    const unsigned long long p0 = ((unsigned long long)key[0] << 32) | (unsigned)(0xFFFFFFFFu - (unsigned)((l0 + 0) * NA + a));
    const unsigned long long p1 = ((unsigned long long)key[1] << 32) | (unsigned)(0xFFFFFFFFu - (unsigned)((l0 + 1) * NA + a));
    const unsigned long long p2 = ((unsigned long long)key[2] << 32) | (unsigned)(0xFFFFFFFFu - (unsigned)((l0 + 2) * NA + a));
    const unsigned long long p3 = ((unsigned long long)key[3] << 32) | (unsigned)(0xFFFFFFFFu - (unsigned)((l0 + 3) * NA + a));
    *(ulonglong2*)&packed[b * NSEL + r]     = make_ulonglong2(p0, p1);
    *(ulonglong2*)&packed[b * NSEL + r + 2] = make_ulonglong2(p2, p3);
    *(float4*)&prop[b * NSEL + r]     = make_float4(x1v[0], x2v[0], x1v[1], x2v[1]);
    *(float4*)&prop[b * NSEL + r + 2] = make_float4(x1v[2], x2v[2], x1v[3], x2v[3]);

    #pragma unroll
    for (int k = 0; k < 4; ++k) atomicAdd(&shist[key[k] >> 20], 1u);
    __syncthreads();

    // plain-store partial hist to this block's own slot (no zeroing, no atomics)
    ((uint4*)&hpart[(b * 10 + a) << 12])[tid] = ((const uint4*)shist)[tid];
}

// ---------------- Kernel 2: fused kmin + deterministic compact + rank + scatter ----------------
// Round-7 post-mortem: k_select's only outputs (kmin, survivor list) are derivable
// REDUNDANTLY per rank-block with no cross-block communication: (1) kmin from hpart
// (160 KB L2/L3-hot reads, identical suffix-scan semantics); (2) compaction into LDS in
// a FIXED canonical order (thread-contiguous ownership + one block scan, no atomics) so
// all 16 blocks of an image build the IDENTICAL list -> candidate ownership by list
// position is consistent. List order is irrelevant to ranks (rank = #{key_j > key_i},
// keys unique). Deletes the k_select node + cand/gcnt buffers.
__global__ __launch_bounds__(256) void k_rank(const unsigned long long* __restrict__ packed,
                                              const unsigned* __restrict__ hpart,
                                              const float2* __restrict__ prop,
                                              float2* __restrict__ srt) {
    __shared__ __align__(16) unsigned long long keys[CAND];   // 32 KB
    __shared__ unsigned part[4][64][4];                        // 4 KB partial ranks
    __shared__ unsigned swsum[4];
    __shared__ int scnt[4];
    __shared__ unsigned skmin;

    const int tid = threadIdx.x;
    const int lane = tid & 63;
    const int wv = tid >> 6;
    const int b = blockIdx.y;
    const int ib = blockIdx.x * 256;

    // --- Phase 1: kmin from hpart (thread owns buckets [16t, 16t+16), r7-identical semantics) ---
    unsigned h[16];
    {
        #pragma unroll
        for (int k = 0; k < 16; ++k) h[k] = 0;
        #pragma unroll
        for (int c = 0; c < 10; ++c) {
            const uint4* hp = (const uint4*)&hpart[((b * 10 + c) << 12) + (tid << 4)];
            #pragma unroll
            for (int q = 0; q < 4; ++q) {
                const uint4 v = hp[q];
                h[q * 4 + 0] += v.x; h[q * 4 + 1] += v.y;
                h[q * 4 + 2] += v.z; h[q * 4 + 3] += v.w;
            }
        }
    }
    unsigned s = 0;
    #pragma unroll
    for (int k = 0; k < 16; ++k) s += h[k];

    {   // wave suffix-scan (incl self) + cross-wave
        unsigned inc = s;
        #pragma unroll
        for (int d = 1; d < 64; d <<= 1) {
            unsigned u = (unsigned)__shfl_down((int)inc, d, 64);
            if (lane + d < 64) inc += u;
        }
        if (lane == 0) swsum[wv] = inc;
        __syncthreads();
        unsigned after = 0;
        for (int w2 = wv + 1; w2 < 4; ++w2) after += swsum[w2];
        const unsigned glob = inc + after;       // suffix including my 16 buckets
        unsigned cum = glob - s;                 // strictly above my group
        #pragma unroll
        for (int k = 15; k >= 0; --k) {          // descending buckets within my group
            cum += h[k];
            if (cum >= (unsigned)PRE2 && (cum - h[k]) < (unsigned)PRE2)
                skmin = ((unsigned)((tid << 4) + k)) << 20;
        }
    }
    __syncthreads();
    const unsigned kmin = skmin;

    // --- Phase 2: deterministic compact (canonical order = (thread, i) lexicographic) ---
    // Thread t owns packed elements [t*160, t*160+160) read as pk[i*256+tid]? NO —
    // ownership must be contiguous in the CANONICAL order; use strided reads with
    // thread-local order: canonical order is by (tid, i) with element index i*256+tid.
    // Reads pk[i*256+tid] are fully coalesced per i; same fixed permutation in every block.
    const unsigned long long* pk = packed + b * NSEL;
    int cnt = 0;
    #pragma unroll 8
    for (int i = 0; i < 160; ++i)
        cnt += (int)((unsigned)(pk[i * 256 + tid] >> 32) >= kmin);

    // block exclusive scan over 256 per-thread counts (tid order)
    int incp = cnt;
    #pragma unroll
    for (int d = 1; d < 64; d <<= 1) {
        int u = __shfl_up(incp, d, 64);
        if (lane >= d) incp += u;
    }
    if (lane == 63) scnt[wv] = incp;
    __syncthreads();
    int waveoff = 0;
    for (int w2 = 0; w2 < wv; ++w2) waveoff += scnt[w2];
    int pos = waveoff + incp - cnt;              // exclusive prefix in tid order
    int n = scnt[0] + scnt[1] + scnt[2] + scnt[3];
    if (n > CAND) n = CAND;
    const int nP = (n + 7) & ~7;

    #pragma unroll 4
    for (int i = 0; i < 160; ++i) {
        const unsigned long long e = pk[i * 256 + tid];
        if ((unsigned)(e >> 32) >= kmin) {
            if (pos < CAND) keys[pos] = e;
            ++pos;
        }
    }
    for (int j = n + tid; j < nP; j += 256) keys[j] = 0ULL;   // pad (0 never outranks)
    __syncthreads();

    // --- Phase 3: rank + scatter (r7-identical) ---
    if (ib < n) {
        const int i0 = ib + (lane << 2);
        const unsigned long long k0 = keys[i0 + 0];
        const unsigned long long k1 = keys[i0 + 1];
        const unsigned long long k2 = keys[i0 + 2];
        const unsigned long long k3 = keys[i0 + 3];

        const int q = nP >> 2;
        const ulonglong2* keys2 = (const ulonglong2*)keys;
        const int p0 = (wv * q) >> 1;
        const int pn = q >> 1;
        unsigned r0 = 0, r1 = 0, r2 = 0, r3 = 0;
        #pragma unroll 4
        for (int p = 0; p < pn; ++p) {
            ulonglong2 kj = keys2[p0 + p];       // broadcast (all lanes same addr): conflict-free
            r0 += (kj.x > k0); r0 += (kj.y > k0);
            r1 += (kj.x > k1); r1 += (kj.y > k1);
            r2 += (kj.x > k2); r2 += (kj.y > k2);
            r3 += (kj.x > k3); r3 += (kj.y > k3);
        }
        part[wv][lane][0] = r0; part[wv][lane][1] = r1;
        part[wv][lane][2] = r2; part[wv][lane][3] = r3;
        __syncthreads();

        const int ig = ib + tid;
        if (ig < n) {
            const int l_ = tid >> 2, c_ = tid & 3;
            unsigned r = part[0][l_][c_] + part[1][l_][c_] + part[2][l_][c_] + part[3][l_][c_];
            if (r < PRE2) {
                unsigned long long k = keys[ig];
                unsigned idx_ = 0xFFFFFFFFu - (unsigned)k;
                unsigned a_ = idx_ % 10u, l2_ = idx_ / 10u;
                srt[b * PRE2 + r] = prop[b * NSEL + (a_ << 12) + l2_];
            }
        }
    }
}

// ---------------- Kernel 3: COLUMN-major suppression mask over top-2048 ----------------
__global__ __launch_bounds__(256) void k_mask(const float2* __restrict__ srt,
                                              unsigned long long* __restrict__ maskT) {
    const int g  = blockIdx.x;          // wi in [4g, 4g+3]
    const int wj = blockIdx.y;
    const int b  = blockIdx.z;
    if (g * 4 > wj) return;             // whole group above diagonal

    __shared__ float2 lj[256];
    const int tid = threadIdx.x;
    lj[tid] = srt[b * PRE2 + (g << 8) + tid];    // suppressor candidates (4 words)
    __syncthreads();

    const int wi = (g << 2) + (tid >> 6);
    if (wi > wj) return;
    const int j = (wj << 6) + (tid & 63);

    float2 pj = srt[b * PRE2 + j];
    float ljn = pj.y - pj.x + 1.0f;
    unsigned long long bits = 0ULL;
    const int lbase = (tid >> 6) * 64;
    const int ibase = wi << 6;
    #pragma unroll 4
    for (int t = 0; t < 64; ++t) {
        float2 pv = lj[lbase + t];
        float inter = fminf(pj.y, pv.y) - fmaxf(pj.x, pv.x) + 1.0f;
        bool sup = false;
        if (inter > 0.0f) {
            float uni = ljn + (pv.y - pv.x + 1.0f) - inter;
            sup = (inter / uni) > 0.7f;          // IEEE div, same rounding as reference
        }
        if ((ibase + t < j) && sup) bits |= (1ULL << t);
    }
    maskT[(size_t)b * TWORDS + (size_t)((wj * (wj + 1) / 2) + wi) * 64 + (tid & 63)] = bits;
}

// ---------------- Kernel 4: single-wave greedy, DEPTH-4 column prefetch pipeline ----------------
// Fixed 16 KB stages (16 VMEM ops each), 4 LDS buffers, counted s_waitcnt vmcnt(48):
// 3 stages stay in flight so each has ~3 windows of compute+greedy to hide latency.
__global__ __launch_bounds__(64, 1) void k_reduce(const unsigned long long* __restrict__ maskT,
                                                  const float2* __restrict__ srt,
                                                  float* __restrict__ out) {
    const int b = blockIdx.x;
    const int lane = threadIdx.x;
    __shared__ unsigned long long colbuf[4][2048];   // 4 x 16 KB
    __shared__ unsigned long long Kl[32];            // kept bitset per window
    __shared__ int sKl[POST_NMS];

    const unsigned long long* mTb = maskT + (size_t)b * TWORDS;

    auto stage = [&](int wv, int buf) {              // fixed 16 KB stage (16 VMEM ops)
        const char* src = (const char*)(mTb + (size_t)(wv * (wv + 1) / 2) * 64) + lane * 16;
        char* dst = (char*)(&colbuf[buf][0]);
        #pragma unroll
        for (int k = 0; k < 16; ++k)
            gload_lds16(src + k * 1024, dst + k * 1024);
    };

    stage(0, 0); stage(1, 1); stage(2, 2); stage(3, 3);   // prologue: 64 ops in flight

    int kept = 0;
    bool done = false;

    for (int w = 0; w < 32 && !done; ++w) {
        // stages w+1..w+3 (48 ops) may stay outstanding; stage w must be complete
        asm volatile("s_waitcnt vmcnt(48)" ::: "memory");
        __builtin_amdgcn_sched_barrier(0);

        const unsigned long long* cw = &colbuf[w & 3][0];
        unsigned long long SUP = 0ULL;
        for (int wi = 0; wi < w; ++wi)
            SUP |= Kl[wi] & cw[(wi << 6) + lane];    // broadcast K read + per-lane col read
        unsigned long long x = cw[(w << 6) + lane];  // within-window suppressor column

        unsigned long long avail = ~__ballot(SUP != 0ULL);
        // retire all LDS reads of this buffer, pin x, THEN reuse the buffer slot for w+4
        asm volatile("s_waitcnt lgkmcnt(0)" ::: "memory");
        __builtin_amdgcn_sched_barrier(0);
        asm volatile("" : "+v"(x));
        {
            int nx = w + 4;
            stage(nx < 31 ? nx : 31, nx & 3);        // nx>=32: dummy re-stage keeps vmcnt invariant
        }

        unsigned long long keptw = 0ULL;
        while (avail) {
            int j = __ffsll((long long)avail) - 1;   // wave-uniform
            if (lane == 0) sKl[kept] = (w << 6) + j;
            kept++; keptw |= (1ULL << j);
            if (kept >= POST_NMS) { done = true; break; }
            unsigned long long supb = __ballot(((x >> j) & 1ULL) != 0ULL);
            avail &= ~supb;
            avail &= ~(1ULL << j);
        }
        if (lane == 0) Kl[w] = keptw;
    }

    __syncthreads();
    for (int t = lane; t < POST_NMS; t += 64) {
        float x1 = 0.0f, x2 = 0.0f;
        if (t < kept) {
            float2 pv = srt[b * PRE2 + sKl[t]];
            x1 = pv.x; x2 = pv.y;
        }
        float* o = out + (size_t)(b * POST_NMS + t) * 3;
        o[0] = (float)b; o[1] = x1; o[2] = x2;
    }
}

extern "C" void kernel_launch(void* const* d_in, const int* in_sizes, int n_in,
                              void* d_out, int out_size, void* d_ws, size_t ws_size,
                              hipStream_t stream) {
    const float* scores = (const float*)d_in[0];
    const float* deltas = (const float*)d_in[1];
    float* out = (float*)d_out;

    char* ws = (char*)d_ws;
    unsigned long long* packed = (unsigned long long*)ws;                   // 1,310,720 B
    float2* prop = (float2*)(ws + 1310720);                                 // 1,310,720 B
    float2* srt  = (float2*)(ws + 2621440);                                 //    65,536 B
    unsigned long long* maskT = (unsigned long long*)(ws + 2686976);        // 1,081,344 B
    unsigned* hpart           = (unsigned*)(ws + 3899408);                  //   655,360 B (40 x 16KB partials)

    k_prep<<<dim3(NA, NB), 1024, 0, stream>>>(scores, deltas, packed, prop, hpart);
    k_rank<<<dim3(CAND / 256, NB), 256, 0, stream>>>(packed, hpart, prop, srt);
    k_mask<<<dim3(8, 32, NB), 256, 0, stream>>>(srt, maskT);
    k_reduce<<<NB, 64, 0, stream>>>(maskT, srt, out);
}

// Round 9
// 71.524 us; speedup vs baseline: 1.3731x; 1.3731x over previous
//
#include <hip/hip_runtime.h>
#include <stdint.h>

#pragma clang fp contract(off)

#define NA 10
#define LL 4096
#define NB 4
#define NSEL (LL * NA)        // 40960 proposals per image
#define PRE2 2048             // NMS candidate window (prefix-stable: 300 kept << 2048)
#define POST_NMS 300
#define CAND 4096             // candidate buffer (12-bit threshold overshoot bound)
#define NHB12 4096            // 12-bit-prefix histogram buckets
#define TWORDS 33792          // col-major mask words per image: 64 * sum_{w=0..31}(w+1)

__constant__ float c_WS[NA] = {16.f, 32.f, 40.f, 48.f, 64.f, 72.f, 80.f, 96.f, 112.f, 128.f};

// async global->LDS DMA: per-lane 16B from g (per-lane addr), lands at uniform dst + lane*16
__device__ inline void gload_lds16(const void* g, void* l) {
    __builtin_amdgcn_global_load_lds(
        (const __attribute__((address_space(1))) unsigned*)g,
        (__attribute__((address_space(3))) unsigned*)l, 16, 0, 0);
}

// ---------------- Kernel 1: decode (1 anchor-row per block) + 12-bit partial hist ----------------
// Wide decode (40 blocks, one per (image,anchor): c_WS[a] scalar, coalesced row reads);
// each block stores a 4096-bucket (key>>20) partial hist to its OWN slot (plain stores:
// no memset node, no global atomics). Block a==0 also zeroes gcnt[b] (kernel boundary
// orders it before k_select's atomics). 12-bit threshold = survivor SUPERSET of top-2048;
// k_rank reconstructs the exact order, so output is bit-identical.
__global__ __launch_bounds__(1024) void k_prep(const float* __restrict__ scores,
                                               const float* __restrict__ deltas,
                                               unsigned long long* __restrict__ packed,
                                               float2* __restrict__ prop,
                                               unsigned* __restrict__ hpart,
                                               int* __restrict__ gcnt) {
    __shared__ unsigned shist[NHB12];    // 16 KB
    const int tid = threadIdx.x;
    const int a = blockIdx.x;            // anchor = row
    const int b = blockIdx.y;

    if (a == 0 && tid == 0) gcnt[b] = 0;

    #pragma unroll
    for (int i = 0; i < 4; ++i) shist[i * 1024 + tid] = 0;
    __syncthreads();

    const float4 s4  = ((const float4*)scores)[((b * 20 + 10 + a) << 10) + tid];
    const float4 d04 = ((const float4*)deltas)[((b * 20 + 2 * a) << 10) + tid];
    const float4 d14 = ((const float4*)deltas)[((b * 20 + 2 * a + 1) << 10) + tid];
    const float w = c_WS[a];
    const int l0 = tid << 2;             // l = 4*tid + k
    const int r = (a << 12) + l0;

    unsigned key[4];
    float x1v[4], x2v[4];
    #pragma unroll
    for (int k = 0; k < 4; ++k) {
        const float d0 = (k == 0) ? d04.x : (k == 1) ? d04.y : (k == 2) ? d04.z : d04.w;
        const float d1 = (k == 0) ? d14.x : (k == 1) ? d14.y : (k == 2) ? d14.z : d14.w;
        float sv      = (k == 0) ? s4.x  : (k == 1) ? s4.y  : (k == 2) ? s4.z  : s4.w;
        const float ctr = (float)(8 * (l0 + k) + 4);
        const float pc = d0 * w + ctr;   // contract(off): mul then add, matches numpy
        const float pl = expf(d1) * w;
        const float x1 = fminf(fmaxf(pc - 0.5f * pl, 0.0f), 32767.0f);
        const float x2 = fminf(fmaxf(pc + 0.5f * pl, 0.0f), 32767.0f);
        if (x2 - x1 + 1.0f < 8.0f) sv = 0.0f;
        const unsigned u = __float_as_uint(sv);
        key[k] = (u & 0x80000000u) ? ~u : (u | 0x80000000u);   // ascending uint == ascending float
        x1v[k] = x1; x2v[k] = x2;
    }
    // packed: reference flat index i = l*NA + a, inverted for descending tie-break
    const unsigned long long p0 = ((unsigned long long)key[0] << 32) | (unsigned)(0xFFFFFFFFu - (unsigned)((l0 + 0) * NA + a));
    const unsigned long long p1 = ((unsigned long long)key[1] << 32) | (unsigned)(0xFFFFFFFFu - (unsigned)((l0 + 1) * NA + a));
    const unsigned long long p2 = ((unsigned long long)key[2] << 32) | (unsigned)(0xFFFFFFFFu - (unsigned)((l0 + 2) * NA + a));
    const unsigned long long p3 = ((unsigned long long)key[3] << 32) | (unsigned)(0xFFFFFFFFu - (unsigned)((l0 + 3) * NA + a));
    *(ulonglong2*)&packed[b * NSEL + r]     = make_ulonglong2(p0, p1);
    *(ulonglong2*)&packed[b * NSEL + r + 2] = make_ulonglong2(p2, p3);
    *(float4*)&prop[b * NSEL + r]     = make_float4(x1v[0], x2v[0], x1v[1], x2v[1]);
    *(float4*)&prop[b * NSEL + r + 2] = make_float4(x1v[2], x2v[2], x1v[3], x2v[3]);

    #pragma unroll
    for (int k = 0; k < 4; ++k) atomicAdd(&shist[key[k] >> 20], 1u);
    __syncthreads();

    // plain-store partial hist to this block's own slot (no zeroing, no atomics)
    ((uint4*)&hpart[(b * 10 + a) << 12])[tid] = ((const uint4*)shist)[tid];
}

// ---------------- Kernel 2: WIDE select: redundant kmin + slice compact (40 blocks) ----------------
// Round-8 post-mortem: full redundant per-block re-derivation (64 blocks x whole image,
// serial compact loop) cost 50us. This keeps r7's proven ballot compact but widens it:
// 10 blocks/image, each redundantly computes kmin from hpart (160KB L2-hot reads, exact
// r7 suffix-scan), then compacts ONLY its own 4096-elem slice (2 x ulonglong2/thread in
// registers) with one global atomicAdd for the base. Survivor set identical; cross-block
// order nondeterministic but irrelevant (k_rank's exact ranking, proven r2->r7).
__global__ __launch_bounds__(1024, 1) void k_select(const unsigned long long* __restrict__ packed,
                                                    const unsigned* __restrict__ hpart,
                                                    unsigned long long* __restrict__ cand,
                                                    int* __restrict__ gcnt) {
    __shared__ unsigned swsum[16];
    __shared__ unsigned skmin;
    __shared__ int wcnt[16];
    __shared__ int sbase;

    const int tid = threadIdx.x;
    const int lane = tid & 63;
    const int wv = tid >> 6;
    const int b = blockIdx.y;

    // --- Phase 1: kmin from hpart (r7-identical: thread owns buckets [4t,4t+3]) ---
    uint4 h = make_uint4(0, 0, 0, 0);
    #pragma unroll
    for (int c = 0; c < 10; ++c) {
        const uint4 v = ((const uint4*)hpart)[((b * 10 + c) << 10) + tid];
        h.x += v.x; h.y += v.y; h.z += v.z; h.w += v.w;
    }
    const unsigned s = h.x + h.y + h.z + h.w;

    unsigned inc = s;
    #pragma unroll
    for (int d = 1; d < 64; d <<= 1) {
        unsigned u = (unsigned)__shfl_down((int)inc, d, 64);
        if (lane + d < 64) inc += u;
    }
    if (lane == 0) swsum[wv] = inc;
    __syncthreads();
    if (tid < 16) {
        unsigned t = swsum[tid];
        unsigned winc = t;
        #pragma unroll
        for (int d = 1; d < 16; d <<= 1) {
            unsigned u = (unsigned)__shfl_down((int)winc, d, 64);
            if (tid + d < 16) winc += u;
        }
        swsum[tid] = winc - t;               // sum of waves strictly after tid
    }
    __syncthreads();
    {
        const unsigned glob = inc + swsum[wv];   // suffix including my 4 buckets
        const unsigned base = glob - s;          // strictly above my quad
        const unsigned t3 = base + h.w;
        const unsigned t2 = t3 + h.z;
        const unsigned t1 = t2 + h.y;
        const unsigned t0 = t1 + h.x;
        const unsigned bx = (unsigned)(tid << 2);
        if (t0 >= (unsigned)PRE2 && t0 - h.x < (unsigned)PRE2) skmin = (bx + 0) << 20;
        if (t1 >= (unsigned)PRE2 && t1 - h.y < (unsigned)PRE2) skmin = (bx + 1) << 20;
        if (t2 >= (unsigned)PRE2 && t2 - h.z < (unsigned)PRE2) skmin = (bx + 2) << 20;
        if (t3 >= (unsigned)PRE2 && t3 - h.w < (unsigned)PRE2) skmin = (bx + 3) << 20;
    }
    __syncthreads();
    const unsigned kmin = skmin;

    // --- Phase 2: compact my 4096-elem slice (all operands in registers) ---
    const unsigned long long* pk = packed + b * NSEL + (blockIdx.x << 12);
    const ulonglong2 e0 = ((const ulonglong2*)pk)[tid];          // elems 2tid, 2tid+1
    const ulonglong2 e1 = ((const ulonglong2*)pk)[1024 + tid];   // elems 2048+2tid, +1

    const bool pa = ((unsigned)(e0.x >> 32) >= kmin);
    const bool pb = ((unsigned)(e0.y >> 32) >= kmin);
    const bool pc = ((unsigned)(e1.x >> 32) >= kmin);
    const bool pd = ((unsigned)(e1.y >> 32) >= kmin);
    const unsigned long long ma = __ballot(pa);
    const unsigned long long mb = __ballot(pb);
    const unsigned long long mc = __ballot(pc);
    const unsigned long long md = __ballot(pd);
    const int ca = (int)__popcll(ma), cb2 = (int)__popcll(mb);
    const int cc = (int)__popcll(mc), cd = (int)__popcll(md);
    if (lane == 0) wcnt[wv] = ca + cb2 + cc + cd;
    __syncthreads();
    if (tid == 0) {
        int t = 0;
        #pragma unroll
        for (int w2 = 0; w2 < 16; ++w2) { int v = wcnt[w2]; wcnt[w2] = t; t += v; }
        sbase = atomicAdd(&gcnt[b], t);      // one global atomic per block
    }
    __syncthreads();
    const int base = sbase + wcnt[wv];
    const unsigned long long below = (1ULL << lane) - 1ULL;
    unsigned long long* cb = cand + b * CAND;
    if (pa) { int p = base + (int)__popcll(ma & below);                 if (p < CAND) cb[p] = e0.x; }
    if (pb) { int p = base + ca + (int)__popcll(mb & below);            if (p < CAND) cb[p] = e0.y; }
    if (pc) { int p = base + ca + cb2 + (int)__popcll(mc & below);      if (p < CAND) cb[p] = e1.x; }
    if (pd) { int p = base + ca + cb2 + cc + (int)__popcll(md & below); if (p < CAND) cb[p] = e1.y; }
}

// ---------------- Kernel 3: rank-scatter, LDS-staged ----------------
// rank_i = #{j : key_j > key_i}: exact descending-sort position (keys unique).
__global__ __launch_bounds__(256) void k_rank(const unsigned long long* __restrict__ cand,
                                              const int* __restrict__ gcnt,
                                              const float2* __restrict__ prop,
                                              float2* __restrict__ srt) {
    __shared__ __align__(16) unsigned long long keys[CAND];   // 32 KB
    __shared__ unsigned part[4][64][4];                        // 4 KB partial ranks

    const int b = blockIdx.y;
    const int n0 = gcnt[b];
    const int n = n0 < CAND ? n0 : CAND;
    const int ib = blockIdx.x * 256;
    if (ib >= n) return;                       // uniform per block: safe before syncs

    const int tid = threadIdx.x;
    const int lane = tid & 63;
    const int wv = tid >> 6;
    const unsigned long long* cb = cand + b * CAND;

    // --- stage: coalesced bulk load, zero-pad to multiple of 8 (0 never outranks a real key) ---
    const int nP = (n + 7) & ~7;
    for (int j = tid; j < nP; j += 256)
        keys[j] = (j < n) ? cb[j] : 0ULL;
    __syncthreads();

    // --- my 4 candidates' keys (i = ib + 4*lane + c); reads past n are pad, guarded later ---
    const int i0 = ib + (lane << 2);
    const unsigned long long k0 = keys[i0 + 0];
    const unsigned long long k1 = keys[i0 + 1];
    const unsigned long long k2 = keys[i0 + 2];
    const unsigned long long k3 = keys[i0 + 3];

    // --- wave wv scans j-slice [wv*q, wv*q+q), q even -> 16B-aligned pair reads ---
    const int q = nP >> 2;
    const ulonglong2* keys2 = (const ulonglong2*)keys;
    const int p0 = (wv * q) >> 1;
    const int pn = q >> 1;
    unsigned r0 = 0, r1 = 0, r2 = 0, r3 = 0;
    #pragma unroll 4
    for (int p = 0; p < pn; ++p) {
        ulonglong2 kj = keys2[p0 + p];         // broadcast (all lanes same addr): conflict-free
        r0 += (kj.x > k0); r0 += (kj.y > k0);
        r1 += (kj.x > k1); r1 += (kj.y > k1);
        r2 += (kj.x > k2); r2 += (kj.y > k2);
        r3 += (kj.x > k3); r3 += (kj.y > k3);
    }
    part[wv][lane][0] = r0; part[wv][lane][1] = r1;
    part[wv][lane][2] = r2; part[wv][lane][3] = r3;
    __syncthreads();

    // --- combine partials, decode, gather box, scatter to rank position ---
    const int ig = ib + tid;
    if (ig < n) {
        const int l_ = tid >> 2, c_ = tid & 3;
        unsigned r = part[0][l_][c_] + part[1][l_][c_] + part[2][l_][c_] + part[3][l_][c_];
        if (r < PRE2) {
            unsigned long long k = keys[ig];
            unsigned idx_ = 0xFFFFFFFFu - (unsigned)k;
            unsigned a_ = idx_ % 10u, l2_ = idx_ / 10u;
            srt[b * PRE2 + r] = prop[b * NSEL + (a_ << 12) + l2_];
        }
    }
}

// ---------------- Kernel 4: COLUMN-major suppression mask over top-2048 ----------------
__global__ __launch_bounds__(256) void k_mask(const float2* __restrict__ srt,
                                              unsigned long long* __restrict__ maskT) {
    const int g  = blockIdx.x;          // wi in [4g, 4g+3]
    const int wj = blockIdx.y;
    const int b  = blockIdx.z;
    if (g * 4 > wj) return;             // whole group above diagonal

    __shared__ float2 lj[256];
    const int tid = threadIdx.x;
    lj[tid] = srt[b * PRE2 + (g << 8) + tid];    // suppressor candidates (4 words)
    __syncthreads();

    const int wi = (g << 2) + (tid >> 6);
    if (wi > wj) return;
    const int j = (wj << 6) + (tid & 63);

    float2 pj = srt[b * PRE2 + j];
    float ljn = pj.y - pj.x + 1.0f;
    unsigned long long bits = 0ULL;
    const int lbase = (tid >> 6) * 64;
    const int ibase = wi << 6;
    #pragma unroll 4
    for (int t = 0; t < 64; ++t) {
        float2 pv = lj[lbase + t];
        float inter = fminf(pj.y, pv.y) - fmaxf(pj.x, pv.x) + 1.0f;
        bool sup = false;
        if (inter > 0.0f) {
            float uni = ljn + (pv.y - pv.x + 1.0f) - inter;
            sup = (inter / uni) > 0.7f;          // IEEE div, same rounding as reference
        }
        if ((ibase + t < j) && sup) bits |= (1ULL << t);
    }
    maskT[(size_t)b * TWORDS + (size_t)((wj * (wj + 1) / 2) + wi) * 64 + (tid & 63)] = bits;
}

// ---------------- Kernel 5: single-wave greedy, DEPTH-4 column prefetch pipeline ----------------
// Fixed 16 KB stages (16 VMEM ops each), 4 LDS buffers, counted s_waitcnt vmcnt(48):
// 3 stages stay in flight so each has ~3 windows of compute+greedy to hide latency.
__global__ __launch_bounds__(64, 1) void k_reduce(const unsigned long long* __restrict__ maskT,
                                                  const float2* __restrict__ srt,
                                                  float* __restrict__ out) {
    const int b = blockIdx.x;
    const int lane = threadIdx.x;
    __shared__ unsigned long long colbuf[4][2048];   // 4 x 16 KB
    __shared__ unsigned long long Kl[32];            // kept bitset per window
    __shared__ int sKl[POST_NMS];

    const unsigned long long* mTb = maskT + (size_t)b * TWORDS;

    auto stage = [&](int wv, int buf) {              // fixed 16 KB stage (16 VMEM ops)
        const char* src = (const char*)(mTb + (size_t)(wv * (wv + 1) / 2) * 64) + lane * 16;
        char* dst = (char*)(&colbuf[buf][0]);
        #pragma unroll
        for (int k = 0; k < 16; ++k)
            gload_lds16(src + k * 1024, dst + k * 1024);
    };

    stage(0, 0); stage(1, 1); stage(2, 2); stage(3, 3);   // prologue: 64 ops in flight

    int kept = 0;
    bool done = false;

    for (int w = 0; w < 32 && !done; ++w) {
        // stages w+1..w+3 (48 ops) may stay outstanding; stage w must be complete
        asm volatile("s_waitcnt vmcnt(48)" ::: "memory");
        __builtin_amdgcn_sched_barrier(0);

        const unsigned long long* cw = &colbuf[w & 3][0];
        unsigned long long SUP = 0ULL;
        for (int wi = 0; wi < w; ++wi)
            SUP |= Kl[wi] & cw[(wi << 6) + lane];    // broadcast K read + per-lane col read
        unsigned long long x = cw[(w << 6) + lane];  // within-window suppressor column

        unsigned long long avail = ~__ballot(SUP != 0ULL);
        // retire all LDS reads of this buffer, pin x, THEN reuse the buffer slot for w+4
        asm volatile("s_waitcnt lgkmcnt(0)" ::: "memory");
        __builtin_amdgcn_sched_barrier(0);
        asm volatile("" : "+v"(x));
        {
            int nx = w + 4;
            stage(nx < 31 ? nx : 31, nx & 3);        // nx>=32: dummy re-stage keeps vmcnt invariant
        }

        unsigned long long keptw = 0ULL;
        while (avail) {
            int j = __ffsll((long long)avail) - 1;   // wave-uniform
            if (lane == 0) sKl[kept] = (w << 6) + j;
            kept++; keptw |= (1ULL << j);
            if (kept >= POST_NMS) { done = true; break; }
            unsigned long long supb = __ballot(((x >> j) & 1ULL) != 0ULL);
            avail &= ~supb;
            avail &= ~(1ULL << j);
        }
        if (lane == 0) Kl[w] = keptw;
    }

    __syncthreads();
    for (int t = lane; t < POST_NMS; t += 64) {
        float x1 = 0.0f, x2 = 0.0f;
        if (t < kept) {
            float2 pv = srt[b * PRE2 + sKl[t]];
            x1 = pv.x; x2 = pv.y;
        }
        float* o = out + (size_t)(b * POST_NMS + t) * 3;
        o[0] = (float)b; o[1] = x1; o[2] = x2;
    }
}

extern "C" void kernel_launch(void* const* d_in, const int* in_sizes, int n_in,
                              void* d_out, int out_size, void* d_ws, size_t ws_size,
                              hipStream_t stream) {
    const float* scores = (const float*)d_in[0];
    const float* deltas = (const float*)d_in[1];
    float* out = (float*)d_out;

    char* ws = (char*)d_ws;
    unsigned long long* packed = (unsigned long long*)ws;                   // 1,310,720 B
    float2* prop = (float2*)(ws + 1310720);                                 // 1,310,720 B
    float2* srt  = (float2*)(ws + 2621440);                                 //    65,536 B
    unsigned long long* maskT = (unsigned long long*)(ws + 2686976);        // 1,081,344 B
    unsigned long long* cand  = (unsigned long long*)(ws + 3768320);        //   131,072 B
    int* gcnt                 = (int*)(ws + 3899392);                       //        16 B
    unsigned* hpart           = (unsigned*)(ws + 3899408);                  //   655,360 B (40 x 16KB partials)

    k_prep<<<dim3(NA, NB), 1024, 0, stream>>>(scores, deltas, packed, prop, hpart, gcnt);
    k_select<<<dim3(10, NB), 1024, 0, stream>>>(packed, hpart, cand, gcnt);
    k_rank<<<dim3(CAND / 256, NB), 256, 0, stream>>>(cand, gcnt, prop, srt);
    k_mask<<<dim3(8, 32, NB), 256, 0, stream>>>(srt, maskT);
    k_reduce<<<NB, 64, 0, stream>>>(maskT, srt, out);
}